// Round 7
// baseline (914.284 us; speedup 1.0000x reference)
//
#include <hip/hip_runtime.h>
#include <math.h>

#define NB   8
#define NC   256
#define ND   64
#define NPIX 4096

typedef short bf16x8 __attribute__((ext_vector_type(8)));   // 8 bf16 (4 VGPRs)
typedef float f32x4  __attribute__((ext_vector_type(4)));
typedef float f32x16 __attribute__((ext_vector_type(16)));

static __device__ __forceinline__ ushort f2bf(float f) {
    uint u = __float_as_uint(f);
    u += 0x7fffu + ((u >> 16) & 1u);      // round-to-nearest-even
    return (ushort)(u >> 16);
}
static __device__ __forceinline__ float bf2f(ushort h) {
    return __uint_as_float(((uint)h) << 16);
}

// ---------------------------------------------------------------------------
// transpose_x: x[b][c][p] f32 -> xt_h/xt_l [b][p][256] bf16 hi/lo.
// ---------------------------------------------------------------------------
__global__ __launch_bounds__(256) void transpose_x(
    const float* __restrict__ x, ushort* __restrict__ xth, ushort* __restrict__ xtl)
{
    __shared__ float tile[64][68];
    const int t = threadIdx.x;
    const int p0 = blockIdx.x * 64, c0 = blockIdx.y * 64, b = blockIdx.z;

    const int cl = t >> 4, p4 = (t & 15) * 4;
    #pragma unroll
    for (int i = 0; i < 4; i++) {
        const int c = cl + 16 * i;
        *(float4*)&tile[c][p4] =
            *(const float4*)&x[((size_t)(b * NC + c0 + c)) * NPIX + p0 + p4];
    }
    __syncthreads();

    const int pl = t & 63, ch = t >> 6;
    float v[16];
    #pragma unroll
    for (int j = 0; j < 16; j++) v[j] = tile[ch * 16 + j][pl];
    ushort h[16], l[16];
    #pragma unroll
    for (int j = 0; j < 16; j++) {
        h[j] = f2bf(v[j]);
        l[j] = f2bf(v[j] - bf2f(h[j]));
    }
    const size_t o = ((size_t)(b * NPIX + p0 + pl)) * 256 + c0 + ch * 16;
    *(uint4*)&xth[o]     = *(uint4*)&h[0];
    *(uint4*)&xth[o + 8] = *(uint4*)&h[8];
    *(uint4*)&xtl[o]     = *(uint4*)&l[0];
    *(uint4*)&xtl[o + 8] = *(uint4*)&l[8];
}

// ---------------------------------------------------------------------------
// transpose_w: W[co][ci][3][3] f32 -> wt[rs][co][ci] bf16 (hi/lo for q,k).
// ---------------------------------------------------------------------------
__global__ __launch_bounds__(256) void transpose_w(
    const float* __restrict__ Wq, const float* __restrict__ Wk,
    const float* __restrict__ Wv,
    ushort* __restrict__ qh, ushort* __restrict__ ql,
    ushort* __restrict__ kh, ushort* __restrict__ kl,
    ushort* __restrict__ vh)
{
    __shared__ float wb[2304];
    const int g = blockIdx.x, t = threadIdx.x;
    const float* src;
    ushort *dh, *dl;
    int co, Co, split;
    if (g < 64)       { src = Wq + (size_t)g * 2304; co = g;       Co = 64;  dh = qh; dl = ql; split = 1; }
    else if (g < 128) { src = Wk + (size_t)(g - 64) * 2304; co = g - 64; Co = 64; dh = kh; dl = kl; split = 1; }
    else              { src = Wv + (size_t)(g - 128) * 2304; co = g - 128; Co = 256; dh = vh; dl = nullptr; split = 0; }

    for (int i = t; i < 2304; i += 256) wb[i] = src[i];
    __syncthreads();
    for (int j = t; j < 2304; j += 256) {
        const int rs = j >> 8, ci = j & 255;
        const float v = wb[ci * 9 + rs];
        const ushort hv = f2bf(v);
        const size_t o = ((size_t)(rs * Co + co)) * 256 + ci;
        dh[o] = hv;
        if (split) dl[o] = f2bf(v - bf2f(hv));
    }
}

// ---------------------------------------------------------------------------
// MFMA conv (q/k, split-bf16 3-term). R2 structure (proven, no spills).
// grid (16 hq, 8 b, 2 {q,k}), dyn LDS 65920 B.
// ---------------------------------------------------------------------------
__global__ __launch_bounds__(256) void conv_split_k(
    const ushort* __restrict__ xth, const ushort* __restrict__ xtl,
    const ushort* __restrict__ wqh, const ushort* __restrict__ wql,
    const ushort* __restrict__ wkh, const ushort* __restrict__ wkl,
    const float* __restrict__ bq, const float* __restrict__ bk,
    ushort* __restrict__ qoh, ushort* __restrict__ qol,
    ushort* __restrict__ koh, ushort* __restrict__ kol)
{
    extern __shared__ char smem[];
    ushort* xsh = (ushort*)smem;                 // [6][66][24]
    ushort* xsl = xsh + 6 * 66 * 24;             // [6][66][24]
    ushort* wsp = xsl + 6 * 66 * 24;             // [9][64][24]
    float*  sbias = (float*)(wsp + 9 * 64 * 24); // [64]

    const int hq = blockIdx.x, b = blockIdx.y, ct = blockIdx.z;
    const ushort* wth = ct ? wkh : wqh;
    const ushort* wtl = ct ? wkl : wql;
    const float*  bias = ct ? bk : bq;
    ushort* outh = ct ? koh : qoh;
    ushort* outl = ct ? kol : qol;

    const int t = threadIdx.x;
    const int wv = t >> 6, lane = t & 63;
    const int l31 = lane & 31, khl = lane >> 5;
    const int lanebase = l31 * 24 + khl * 8;
    const int h = hq * 4 + wv;

    if (t < 64) sbias[t] = bias[t];
    for (int i = t; i < 384; i += 256) {
        const int p = i / 192, r2 = i % 192;
        const int row = r2 / 32, e = (r2 % 32) / 16, ci = r2 & 15;
        (p ? xsl : xsh)[(row * 66 + e * 65) * 24 + ci] = 0;
    }

    f32x16 a00 = {0}, a01 = {0}, a10 = {0}, a11 = {0};  // [ms(co)][ns(pix)]

    for (int ch = 0; ch < 16; ch++) {
        __syncthreads();
        const int ci0 = ch * 16;
        #pragma unroll
        for (int pl2 = 0; pl2 < 2; pl2++) {
            const ushort* src = pl2 ? xtl : xth;
            ushort* dst = pl2 ? xsl : xsh;
            #pragma unroll
            for (int i = 0; i < 3; i++) {
                const int a = i * 256 + t;
                const int cih = a & 1, col = (a >> 1) & 63, row = a >> 7;
                const int hs = hq * 4 + row - 1;
                uint4 val = {0, 0, 0, 0};
                if (hs >= 0 && hs < 64)
                    val = *(const uint4*)&src[((size_t)(b * NPIX + hs * 64 + col)) * 256 + ci0 + cih * 8];
                *(uint4*)&dst[(row * 66 + 1 + col) * 24 + cih * 8] = val;
            }
        }
        #pragma unroll
        for (int i = 0; i < 5; i++) {
            const int a = i * 256 + t;
            if (a < 1152) {
                const int cih = a & 1, co = (a >> 1) & 63, rs = a >> 7;
                uint4 wv4 = *(const uint4*)&wth[((size_t)(rs * 64 + co)) * 256 + ci0 + cih * 8];
                *(uint4*)&wsp[(rs * 64 + co) * 24 + cih * 8] = wv4;
            }
        }
        __syncthreads();
        // pass0: (wh.xh) + (wh.xl)
        #pragma unroll
        for (int rs = 0; rs < 9; rs++) {
            const int r = rs / 3, s = rs % 3;
            bf16x8 A0 = *(const bf16x8*)&wsp[rs * 1536 + lanebase];
            bf16x8 A1 = *(const bf16x8*)&wsp[rs * 1536 + 768 + lanebase];
            const int xo = ((wv + r) * 66 + s) * 24 + lanebase;
            bf16x8 B0h = *(const bf16x8*)&xsh[xo];
            bf16x8 B1h = *(const bf16x8*)&xsh[xo + 768];
            bf16x8 B0l = *(const bf16x8*)&xsl[xo];
            bf16x8 B1l = *(const bf16x8*)&xsl[xo + 768];
            a00 = __builtin_amdgcn_mfma_f32_32x32x16_bf16(A0, B0h, a00, 0, 0, 0);
            a01 = __builtin_amdgcn_mfma_f32_32x32x16_bf16(A0, B1h, a01, 0, 0, 0);
            a10 = __builtin_amdgcn_mfma_f32_32x32x16_bf16(A1, B0h, a10, 0, 0, 0);
            a11 = __builtin_amdgcn_mfma_f32_32x32x16_bf16(A1, B1h, a11, 0, 0, 0);
            a00 = __builtin_amdgcn_mfma_f32_32x32x16_bf16(A0, B0l, a00, 0, 0, 0);
            a01 = __builtin_amdgcn_mfma_f32_32x32x16_bf16(A0, B1l, a01, 0, 0, 0);
            a10 = __builtin_amdgcn_mfma_f32_32x32x16_bf16(A1, B0l, a10, 0, 0, 0);
            a11 = __builtin_amdgcn_mfma_f32_32x32x16_bf16(A1, B1l, a11, 0, 0, 0);
        }
        __syncthreads();
        #pragma unroll
        for (int i = 0; i < 5; i++) {
            const int a = i * 256 + t;
            if (a < 1152) {
                const int cih = a & 1, co = (a >> 1) & 63, rs = a >> 7;
                uint4 wv4 = *(const uint4*)&wtl[((size_t)(rs * 64 + co)) * 256 + ci0 + cih * 8];
                *(uint4*)&wsp[(rs * 64 + co) * 24 + cih * 8] = wv4;
            }
        }
        __syncthreads();
        // pass1: (wl.xh)
        #pragma unroll
        for (int rs = 0; rs < 9; rs++) {
            const int r = rs / 3, s = rs % 3;
            bf16x8 A0 = *(const bf16x8*)&wsp[rs * 1536 + lanebase];
            bf16x8 A1 = *(const bf16x8*)&wsp[rs * 1536 + 768 + lanebase];
            const int xo = ((wv + r) * 66 + s) * 24 + lanebase;
            bf16x8 B0h = *(const bf16x8*)&xsh[xo];
            bf16x8 B1h = *(const bf16x8*)&xsh[xo + 768];
            a00 = __builtin_amdgcn_mfma_f32_32x32x16_bf16(A0, B0h, a00, 0, 0, 0);
            a01 = __builtin_amdgcn_mfma_f32_32x32x16_bf16(A0, B1h, a01, 0, 0, 0);
            a10 = __builtin_amdgcn_mfma_f32_32x32x16_bf16(A1, B0h, a10, 0, 0, 0);
            a11 = __builtin_amdgcn_mfma_f32_32x32x16_bf16(A1, B1h, a11, 0, 0, 0);
        }
    }

    const float4* sb4 = (const float4*)sbias;
    #pragma unroll
    for (int ms = 0; ms < 2; ms++)
        #pragma unroll
        for (int ns = 0; ns < 2; ns++) {
            const f32x16 av = ms ? (ns ? a11 : a10) : (ns ? a01 : a00);
            const int p = h * 64 + ns * 32 + l31;
            #pragma unroll
            for (int g = 0; g < 4; g++) {
                const float4 bi = sb4[ms * 8 + 2 * g + khl];
                float v0 = av[4 * g + 0] + bi.x;
                float v1 = av[4 * g + 1] + bi.y;
                float v2 = av[4 * g + 2] + bi.z;
                float v3 = av[4 * g + 3] + bi.w;
                ushort4 hv, lv;
                hv.x = f2bf(v0); lv.x = f2bf(v0 - bf2f(hv.x));
                hv.y = f2bf(v1); lv.y = f2bf(v1 - bf2f(hv.y));
                hv.z = f2bf(v2); lv.z = f2bf(v2 - bf2f(hv.z));
                hv.w = f2bf(v3); lv.w = f2bf(v3 - bf2f(hv.w));
                const size_t o = ((size_t)(b * NPIX + p)) * 64 + ms * 32 + 8 * g + 4 * khl;
                *(ushort4*)&outh[o] = hv;
                *(ushort4*)&outl[o] = lv;
            }
        }
}

// ---------------------------------------------------------------------------
// MFMA conv (v, plain bf16). R2 structure. grid (16 hq, 8 b, 4 cotile),
// dyn LDS 46912 B.
// ---------------------------------------------------------------------------
__global__ __launch_bounds__(256) void conv_v_k(
    const ushort* __restrict__ xth, const ushort* __restrict__ wtv,
    const float* __restrict__ bv, ushort* __restrict__ vout)
{
    extern __shared__ char smem[];
    ushort* xsh = (ushort*)smem;                 // [6][66][24]
    ushort* wsp = xsh + 6 * 66 * 24;             // [9][64][24]
    float*  sbias = (float*)(wsp + 9 * 64 * 24); // [64]

    const int hq = blockIdx.x, b = blockIdx.y, co0 = blockIdx.z * 64;
    const int t = threadIdx.x;
    const int wv = t >> 6, lane = t & 63;
    const int l31 = lane & 31, khl = lane >> 5;
    const int lanebase = l31 * 24 + khl * 8;
    const int h = hq * 4 + wv;

    if (t < 64) sbias[t] = bv[co0 + t];
    for (int i = t; i < 192; i += 256) {
        const int row = i / 32, e = (i % 32) / 16, ci = i & 15;
        xsh[(row * 66 + e * 65) * 24 + ci] = 0;
    }

    f32x16 a00 = {0}, a01 = {0}, a10 = {0}, a11 = {0};  // [ms(pix)][ns(co)]

    for (int ch = 0; ch < 16; ch++) {
        __syncthreads();
        const int ci0 = ch * 16;
        #pragma unroll
        for (int i = 0; i < 3; i++) {
            const int a = i * 256 + t;
            const int cih = a & 1, col = (a >> 1) & 63, row = a >> 7;
            const int hs = hq * 4 + row - 1;
            uint4 val = {0, 0, 0, 0};
            if (hs >= 0 && hs < 64)
                val = *(const uint4*)&xth[((size_t)(b * NPIX + hs * 64 + col)) * 256 + ci0 + cih * 8];
            *(uint4*)&xsh[(row * 66 + 1 + col) * 24 + cih * 8] = val;
        }
        #pragma unroll
        for (int i = 0; i < 5; i++) {
            const int a = i * 256 + t;
            if (a < 1152) {
                const int cih = a & 1, co = (a >> 1) & 63, rs = a >> 7;
                uint4 wv4 = *(const uint4*)&wtv[((size_t)(rs * 256 + co0 + co)) * 256 + ci0 + cih * 8];
                *(uint4*)&wsp[(rs * 64 + co) * 24 + cih * 8] = wv4;
            }
        }
        __syncthreads();
        #pragma unroll
        for (int rs = 0; rs < 9; rs++) {
            const int r = rs / 3, s = rs % 3;
            const int xo = ((wv + r) * 66 + s) * 24 + lanebase;
            bf16x8 A0 = *(const bf16x8*)&xsh[xo];
            bf16x8 A1 = *(const bf16x8*)&xsh[xo + 768];
            bf16x8 B0 = *(const bf16x8*)&wsp[rs * 1536 + lanebase];
            bf16x8 B1 = *(const bf16x8*)&wsp[rs * 1536 + 768 + lanebase];
            a00 = __builtin_amdgcn_mfma_f32_32x32x16_bf16(A0, B0, a00, 0, 0, 0);
            a01 = __builtin_amdgcn_mfma_f32_32x32x16_bf16(A0, B1, a01, 0, 0, 0);
            a10 = __builtin_amdgcn_mfma_f32_32x32x16_bf16(A1, B0, a10, 0, 0, 0);
            a11 = __builtin_amdgcn_mfma_f32_32x32x16_bf16(A1, B1, a11, 0, 0, 0);
        }
    }

    #pragma unroll
    for (int ns = 0; ns < 2; ns++) {
        const int co = co0 + ns * 32 + l31;
        const float bi = sbias[ns * 32 + l31];
        #pragma unroll
        for (int ms = 0; ms < 2; ms++) {
            const f32x16 av = ms ? (ns ? a11 : a10) : (ns ? a01 : a00);
            #pragma unroll
            for (int g = 0; g < 4; g++) {
                const int p = h * 64 + ms * 32 + 8 * g + 4 * khl;
                ushort4 ov;
                ov.x = f2bf(av[4 * g + 0] + bi);
                ov.y = f2bf(av[4 * g + 1] + bi);
                ov.z = f2bf(av[4 * g + 2] + bi);
                ov.w = f2bf(av[4 * g + 3] + bi);
                *(ushort4*)&vout[((size_t)(b * NC + co)) * NPIX + p] = ov;
            }
        }
    }
}

// ---------------------------------------------------------------------------
// MFMA flash attention v5 — BARRIER-FREE, LDS-FREE.
// grid 512 1-D (b = id&7 -> XCD pin; both blocks on a CU share batch b),
// block 256 (4 waves). Each wave owns a 16-row m-slice, fully independent.
//
// Trick: QK-MFMA #q loads K rows n = n0 + 32(q>>1)+4(q&1) + 8(l16>>2)+(l16&3).
// Then S^T C-layout output (q,quad,r) is exactly P[m=l16][n=32ks+8quad+4(q&1)+r]
// = the PV A-fragment element. P lives entirely in registers: no LDS round
// trip, no __syncthreads, no vmcnt(0) barrier drain.
// ---------------------------------------------------------------------------
__global__ __launch_bounds__(256, 2) void attn_k(
    const ushort* __restrict__ qh, const ushort* __restrict__ ql,
    const ushort* __restrict__ kh, const ushort* __restrict__ kl,
    const ushort* __restrict__ vb, const float* __restrict__ x,
    float* __restrict__ out)
{
    const int id = blockIdx.x;
    const int b  = id & 7;                 // XCD-pinned batch
    const int m0 = (id >> 3) * 64;         // block m-tile
    const int t  = threadIdx.x;
    const int w  = t >> 6;
    const int lane = t & 63;
    const int quad = lane >> 4;
    const int l16  = lane & 15;
    const int mw = m0 + 16 * w;            // this wave's m-slice base

    // hoisted Q B-frags: B[col=m=l16][k=d=32ks+8quad+j]
    bf16x8 aqh[2], aql[2];
    #pragma unroll
    for (int ks = 0; ks < 2; ks++) {
        const size_t g = ((size_t)b * NPIX + mw + l16) * ND + 32 * ks + 8 * quad;
        aqh[ks] = *(const bf16x8*)&qh[g];
        aql[ks] = *(const bf16x8*)&ql[g];
    }

    // permuted K row offset for this lane (see header comment)
    const int krow_off = 8 * (l16 >> 2) + (l16 & 3);
    const size_t kbase = ((size_t)b * NPIX + krow_off) * ND + 8 * quad;
    // V base: c = 16ct + l16, n-offset 8quad
    const size_t vbase = ((size_t)b * NC + l16) * NPIX + 8 * quad;

    f32x4 acc[16];
    #pragma unroll
    for (int i = 0; i < 16; i++) acc[i] = (f32x4){0.f, 0.f, 0.f, 0.f};
    float lsum = 0.f;

    for (int n0 = 0; n0 < NPIX; n0 += 64) {
        // ---- QK: 4 MFMA-tiles, K rows permuted so P lands in A-layout ----
        ushort pu[16];
        #pragma unroll
        for (int q = 0; q < 4; q++) {
            const int qb = 32 * (q >> 1) + 4 * (q & 1);
            const size_t ka = kbase + (size_t)(n0 + qb) * ND;
            bf16x8 k0h = *(const bf16x8*)&kh[ka];
            bf16x8 k0l = *(const bf16x8*)&kl[ka];
            bf16x8 k1h = *(const bf16x8*)&kh[ka + 32];
            bf16x8 k1l = *(const bf16x8*)&kl[ka + 32];
            f32x4 s = {0.f, 0.f, 0.f, 0.f};
            s = __builtin_amdgcn_mfma_f32_16x16x32_bf16(k0h, aqh[0], s, 0, 0, 0);
            s = __builtin_amdgcn_mfma_f32_16x16x32_bf16(k0l, aqh[0], s, 0, 0, 0);
            s = __builtin_amdgcn_mfma_f32_16x16x32_bf16(k0h, aql[0], s, 0, 0, 0);
            s = __builtin_amdgcn_mfma_f32_16x16x32_bf16(k1h, aqh[1], s, 0, 0, 0);
            s = __builtin_amdgcn_mfma_f32_16x16x32_bf16(k1l, aqh[1], s, 0, 0, 0);
            s = __builtin_amdgcn_mfma_f32_16x16x32_bf16(k1h, aql[1], s, 0, 0, 0);
            const ushort p0 = f2bf(__expf(s[0] - 30.f));
            const ushort p1 = f2bf(__expf(s[1] - 30.f));
            const ushort p2 = f2bf(__expf(s[2] - 30.f));
            const ushort p3 = f2bf(__expf(s[3] - 30.f));
            lsum += (bf2f(p0) + bf2f(p1)) + (bf2f(p2) + bf2f(p3));
            const int o = (q >> 1) * 8 + 4 * (q & 1);
            pu[o + 0] = p0; pu[o + 1] = p1; pu[o + 2] = p2; pu[o + 3] = p3;
        }
        const bf16x8 ap0 = *(const bf16x8*)&pu[0];
        const bf16x8 ap1 = *(const bf16x8*)&pu[8];

        // ---- PV: A = P (regs), B = V frags direct from global ----
        #pragma unroll
        for (int ct = 0; ct < 16; ct++) {
            const size_t va = vbase + (size_t)ct * 16 * NPIX + n0;
            bf16x8 v0 = *(const bf16x8*)&vb[va];
            bf16x8 v1 = *(const bf16x8*)&vb[va + 32];
            acc[ct] = __builtin_amdgcn_mfma_f32_16x16x32_bf16(ap0, v0, acc[ct], 0, 0, 0);
            acc[ct] = __builtin_amdgcn_mfma_f32_16x16x32_bf16(ap1, v1, acc[ct], 0, 0, 0);
        }
    }

    // rowsum: lane's partials cover m=l16; reduce across quads (lane bits 4,5)
    lsum += __shfl_xor(lsum, 16, 64);
    lsum += __shfl_xor(lsum, 32, 64);
    const float inv = 1.f / lsum;                 // total for m = l16
    float il[4];
    #pragma unroll
    for (int r = 0; r < 4; r++)                   // need inv for m = 4quad + r
        il[r] = __uint_as_float(
            __builtin_amdgcn_ds_bpermute(4 * (4 * quad + r), __float_as_uint(inv)));

    // epilogue: out = acc/l + x ; D rows m = mw + 4quad + r, col c = 16ct+l16
    const int mm = mw + 4 * quad;
    #pragma unroll
    for (int ct = 0; ct < 16; ct++) {
        const int c = 16 * ct + l16;
        const size_t base = ((size_t)b * NC + c) * NPIX + mm;
        const float4 xv = *(const float4*)&x[base];
        const f32x4 a = acc[ct];
        float4 o;
        o.x = fmaf(a[0], il[0], xv.x);
        o.y = fmaf(a[1], il[1], xv.y);
        o.z = fmaf(a[2], il[2], xv.z);
        o.w = fmaf(a[3], il[3], xv.w);
        *(float4*)&out[base] = o;
    }
}

extern "C" void kernel_launch(void* const* d_in, const int* in_sizes, int n_in,
                              void* d_out, int out_size, void* d_ws, size_t ws_size,
                              hipStream_t stream)
{
    const float* x  = (const float*)d_in[0];
    const float* Wq = (const float*)d_in[1];
    const float* bq = (const float*)d_in[2];
    const float* Wk = (const float*)d_in[3];
    const float* bk = (const float*)d_in[4];
    const float* Wv = (const float*)d_in[5];
    const float* bv = (const float*)d_in[6];
    float* outp = (float*)d_out;

    const size_t XT = (size_t)NB * NPIX * 256;   // 8,388,608
    const size_t QK = (size_t)NB * NPIX * ND;    // 2,097,152
    ushort* xt_h = (ushort*)d_ws;
    ushort* xt_l = xt_h + XT;
    ushort* v_b  = xt_l;              // alias: conv_v (after conv_split) overwrites xt_l
    ushort* q_h  = xt_l + XT;
    ushort* q_l  = q_h + QK;
    ushort* k_h  = q_l + QK;
    ushort* k_l  = k_h + QK;
    ushort* wtq_h = k_l + QK;         // 9*64*256 = 147456 each
    ushort* wtq_l = wtq_h + 147456;
    ushort* wtk_h = wtq_l + 147456;
    ushort* wtk_l = wtk_h + 147456;
    ushort* wtv_h = wtk_l + 147456;   // 9*256*256 = 589824

    dim3 blk(256);
    transpose_x<<<dim3(64, 4, NB), blk, 0, stream>>>(x, xt_h, xt_l);
    transpose_w<<<dim3(384), blk, 0, stream>>>(Wq, Wk, Wv, wtq_h, wtq_l, wtk_h, wtk_l, wtv_h);
    conv_split_k<<<dim3(16, NB, 2), blk, 65920, stream>>>(
        xt_h, xt_l, wtq_h, wtq_l, wtk_h, wtk_l, bq, bk, q_h, q_l, k_h, k_l);
    conv_v_k<<<dim3(16, NB, 4), blk, 46912, stream>>>(xt_h, wtv_h, bv, v_b);
    attn_k<<<dim3(512), blk, 0, stream>>>(q_h, q_l, k_h, k_l, v_b, x, outp);
}